// Round 1
// baseline (107.405 us; speedup 1.0000x reference)
//
#include <hip/hip_runtime.h>
#include <cstddef>

// YOLO decode: x[N, A*(C+5), H, W] fp32 -> out[N, A*H*W, C+5] fp32
// N=32, A=3, C=80, H=W=80, IMG=640 (scale = IMG*IMG = 409600 on boxes)
// anchors: (10,13),(16,30),(33,23)

#define HWQ   6400   // H*W
#define WQ    80
#define CH    85     // C+5
#define TILE  64     // spatial positions per block

__device__ __forceinline__ float sigmoidf_(float v) {
    return 1.0f / (1.0f + __expf(-v));
}

__global__ __launch_bounds__(256) void yolo_decode_kernel(
    const float* __restrict__ x, float* __restrict__ out)
{
    const int tile = blockIdx.x;   // 0..99   (HW/TILE)
    const int a    = blockIdx.y;   // 0..2
    const int n    = blockIdx.z;   // 0..31
    const int tid  = threadIdx.x;

    __shared__ float lds[CH * 65]; // pad 64 -> 65 to break bank aliasing

    const int sp_base = tile * TILE;
    const float* inp = x + ((size_t)(n * 3 + a) * CH) * HWQ + sp_base;

    // ---- load: coalesced float4 along spatial dim, one channel per 16-lane run
    for (int i = tid; i < CH * (TILE / 4); i += 256) {
        const int ch = i >> 4;        // / (TILE/4)
        const int s4 = i & 15;        // % (TILE/4)
        const float4 v = *reinterpret_cast<const float4*>(inp + (size_t)ch * HWQ + s4 * 4);
        float* p = &lds[ch * 65 + s4 * 4];
        p[0] = v.x; p[1] = v.y; p[2] = v.z; p[3] = v.w;
    }
    __syncthreads();

    const float aw = (a == 0) ? 10.0f : ((a == 1) ? 16.0f : 33.0f);
    const float ah = (a == 0) ? 13.0f : ((a == 1) ? 30.0f : 23.0f);
    const float awس = aw * 409600.0f;
    const float ahس = ah * 409600.0f;

    // ---- store: contiguous 5440-float output block, float4 coalesced
    float* outp = out + (size_t)((n * 3 + a) * HWQ + sp_base) * CH;
    for (int i = tid; i < CH * (TILE / 4); i += 256) {
        const int j = i * 4;          // element offset within output block
        float r[4];
#pragma unroll
        for (int t = 0; t < 4; ++t) {
            const int jj = j + t;
            const int s  = jj / CH;       // spatial within tile (compiler: magic mul)
            const int c  = jj - s * CH;   // channel 0..84
            float v = lds[c * 65 + s];
            if (c >= 4) {
                v = sigmoidf_(v);                               // obj + class conf
            } else if (c == 0) {
                const int sp = sp_base + s;
                v = (sigmoidf_(v) + (float)(sp % WQ)) * 409600.0f;   // x + grid_x
            } else if (c == 1) {
                const int sp = sp_base + s;
                v = (sigmoidf_(v) + (float)(sp / WQ)) * 409600.0f;   // y + grid_y
            } else if (c == 2) {
                v = __expf(v) * awس;                                 // w * anchor_w
            } else {
                v = __expf(v) * ahس;                                 // h * anchor_h
            }
            r[t] = v;
        }
        float4 o; o.x = r[0]; o.y = r[1]; o.z = r[2]; o.w = r[3];
        *reinterpret_cast<float4*>(outp + j) = o;
    }
}

extern "C" void kernel_launch(void* const* d_in, const int* in_sizes, int n_in,
                              void* d_out, int out_size, void* d_ws, size_t ws_size,
                              hipStream_t stream)
{
    const float* x = (const float*)d_in[0];
    float* out = (float*)d_out;
    dim3 grid(HWQ / TILE, 3, 32);   // (100, A, N)
    dim3 block(256);
    yolo_decode_kernel<<<grid, block, 0, stream>>>(x, out);
}

// Round 2
// 96.030 us; speedup vs baseline: 1.1184x; 1.1184x over previous
//
#include <hip/hip_runtime.h>
#include <cstddef>

// YOLO decode: x[N, A*(C+5), H, W] fp32 -> out[N, A*H*W, C+5] fp32
// N=32, A=3, C=80, H=W=80, IMG=640 (scale = IMG*IMG = 409600 on boxes)
// anchors: (10,13),(16,30),(33,23)

#define HWQ   6400   // H*W
#define WQ    80
#define CH    85     // C+5
#define TILE  64     // spatial positions per block
#define SCALE 409600.0f

__global__ __launch_bounds__(256) void yolo_decode_kernel(
    const float* __restrict__ x, float* __restrict__ out)
{
    const int tile = blockIdx.x;   // 0..99   (HW/TILE)
    const int a    = blockIdx.y;   // 0..2
    const int n    = blockIdx.z;   // 0..31
    const int tid  = threadIdx.x;

    // spatial-major: element (s, c) at lds[s*85 + c].
    // Read phase: contiguous b128 (conflict-free, addr == output offset).
    // Write phase: dword stride 340 -> bank stride 20 per 16-lane group,
    // +1 bank shift per group -> 2 lanes/bank = free.
    __shared__ __align__(16) float lds[TILE * CH];  // 21760 B

    const int sp_base = tile * TILE;
    const float* inp = x + ((size_t)(n * 3 + a) * CH) * HWQ + sp_base;

    // ---- load: coalesced float4 along spatial dim, scatter to spatial-major LDS
    for (int i = tid; i < CH * (TILE / 4); i += 256) {
        const int ch = i >> 4;        // channel 0..84
        const int s4 = i & 15;        // spatial quad 0..15
        const float4 v = *reinterpret_cast<const float4*>(inp + (size_t)ch * HWQ + s4 * 4);
        const int sb = s4 * 4;
        lds[(sb + 0) * CH + ch] = v.x;
        lds[(sb + 1) * CH + ch] = v.y;
        lds[(sb + 2) * CH + ch] = v.z;
        lds[(sb + 3) * CH + ch] = v.w;
    }
    __syncthreads();

    const float awS = ((a == 0) ? 10.0f : ((a == 1) ? 16.0f : 33.0f)) * SCALE;
    const float ahS = ((a == 0) ? 13.0f : ((a == 1) ? 30.0f : 23.0f)) * SCALE;

    float* outp = out + (size_t)((n * 3 + a) * HWQ + sp_base) * CH;

    // per-thread incremental state for element jj = 4*tid:
    //   c_ = jj % 85, spatial s = jj / 85, sp = sp_base + s, gy_ = sp / 80, gx_ = sp % 80
    {
        const int jj0 = tid * 4;
        int s  = jj0 / CH;                // one magic-mul div per thread
        int c_ = jj0 - s * CH;
        int sp = sp_base + s;
        int gy_ = sp / WQ;
        int gx_ = sp - gy_ * WQ;

        for (int i = tid; i < CH * (TILE / 4); i += 256) {
            const float4 v4 = *reinterpret_cast<const float4*>(&lds[i * 4]);
            const float vv[4] = {v4.x, v4.y, v4.z, v4.w};
            float r[4];

            int ct = c_, gxt = gx_, gyt = gy_;
#pragma unroll
            for (int t = 0; t < 4; ++t) {
                const float v = vv[t];
                const bool iswh = (ct == 2) | (ct == 3);
                const float e  = __expf(iswh ? v : -v);
                const float sg = __builtin_amdgcn_rcpf(1.0f + e);
                float res = sg;                                  // c>=4 (and base)
                res = (ct == 0) ? (sg + (float)gxt) * SCALE : res;
                res = (ct == 1) ? (sg + (float)gyt) * SCALE : res;
                res = (ct == 2) ? e * awS : res;
                res = (ct == 3) ? e * ahS : res;
                r[t] = res;

                // advance one element: c wraps at 85 -> next spatial (gx wraps at 80)
                ct += 1;
                const bool w = (ct == CH);
                ct = w ? 0 : ct;
                const int ngx = gxt + 1;
                const bool w2 = (ngx == WQ);
                gxt = w ? (w2 ? 0 : ngx) : gxt;
                gyt = (w && w2) ? (gyt + 1) : gyt;
            }

            float4 o; o.x = r[0]; o.y = r[1]; o.z = r[2]; o.w = r[3];
            *reinterpret_cast<float4*>(outp + i * 4) = o;

            // advance base: next jj is (jj+4) + 1020, and 1020 == 12*85 exactly,
            // so channel stays, spatial advances by 12.
            c_ = ct;
            int ngx2 = gxt + 12;
            if (ngx2 >= WQ) { ngx2 -= WQ; gyt += 1; }
            gx_ = ngx2;
            gy_ = gyt;
        }
    }
}

extern "C" void kernel_launch(void* const* d_in, const int* in_sizes, int n_in,
                              void* d_out, int out_size, void* d_ws, size_t ws_size,
                              hipStream_t stream)
{
    const float* x = (const float*)d_in[0];
    float* out = (float*)d_out;
    dim3 grid(HWQ / TILE, 3, 32);   // (100, A, N)
    dim3 block(256);
    yolo_decode_kernel<<<grid, block, 0, stream>>>(x, out);
}

// Round 4
// 65.822 us; speedup vs baseline: 1.6318x; 1.4589x over previous
//
#include <hip/hip_runtime.h>
#include <cstddef>

// YOLO decode: x[N, A*(C+5), H, W] fp32 -> out[N, A*H*W, C+5] fp32
// N=32, A=3, C=80, H=W=80, IMG=640 (scale = IMG*IMG = 409600 on boxes)
// anchors: (10,13),(16,30),(33,23)
//
// Transform is applied in the LOAD phase, where channel = i>>4 is constant
// per 16-lane group and per float4 -> all channel selects amortize over 4
// elements; per element only {mul, exp, add, rcp, sel, add, mul} remain.
// Store phase is a pure LDS->global contiguous copy (nontemporal: output is
// write-once; keep L3 for the input, which IS re-read every replay).

#define HWQ   6400   // H*W
#define WQ    80
#define CH    85     // C+5
#define TILE  64     // spatial positions per block
#define SCALE 409600.0f

typedef float f32x4 __attribute__((ext_vector_type(4)));

__global__ __launch_bounds__(256) void yolo_decode_kernel(
    const float* __restrict__ x, float* __restrict__ out)
{
    const int tile = blockIdx.x;   // 0..99   (HW/TILE)
    const int a    = blockIdx.y;   // 0..2
    const int n    = blockIdx.z;   // 0..31
    const int tid  = threadIdx.x;

    // spatial-major: element (s, c) at lds[s*85 + c].
    // Write phase: dword stride 340 per s4-step -> bank stride 20, +1 per
    // channel group -> 2 lanes/bank = free. Read phase: contiguous b128.
    __shared__ __align__(16) float lds[TILE * CH];  // 21760 B

    const int sp_base = tile * TILE;
    const float* inp = x + ((size_t)(n * 3 + a) * CH) * HWQ + sp_base;

    const float awS = ((a == 0) ? 10.0f : ((a == 1) ? 16.0f : 33.0f)) * SCALE;
    const float ahS = ((a == 0) ? 13.0f : ((a == 1) ? 30.0f : 23.0f)) * SCALE;

    // ---- load + transform: coalesced float4 along spatial, channel uniform per quad
    for (int i = tid; i < CH * (TILE / 4); i += 256) {
        const int ch = i >> 4;        // channel 0..84 (constant for this quad)
        const int s4 = i & 15;        // spatial quad 0..15
        const f32x4 v = *reinterpret_cast<const f32x4*>(inp + (size_t)ch * HWQ + s4 * 4);

        const bool  iswh = (ch == 2) | (ch == 3);
        const float sgn  = iswh ? 1.0f : -1.0f;

        const int sp0 = sp_base + s4 * 4;
        const int gy0 = sp0 / WQ;
        const int gx0 = sp0 - gy0 * WQ;   // multiple of 4 -> gx0+3 <= 79, no wrap
        float addf = (ch == 0) ? (float)gx0 : ((ch == 1) ? (float)gy0 : 0.0f);
        const float step = (ch == 0) ? 1.0f : 0.0f;
        const float mulc = (ch < 2) ? SCALE
                         : ((ch == 2) ? awS : ((ch == 3) ? ahS : 1.0f));

        float r[4];
#pragma unroll
        for (int t = 0; t < 4; ++t) {
            const float e    = __expf(v[t] * sgn);
            const float sg   = __builtin_amdgcn_rcpf(1.0f + e);
            const float base = iswh ? e : sg;
            r[t] = (base + addf) * mulc;   // ch>=4: (sg+0)*1 = sigmoid exactly
            addf += step;
        }

        const int sb = s4 * 4;
        lds[(sb + 0) * CH + ch] = r[0];
        lds[(sb + 1) * CH + ch] = r[1];
        lds[(sb + 2) * CH + ch] = r[2];
        lds[(sb + 3) * CH + ch] = r[3];
    }
    __syncthreads();

    // ---- store: pure contiguous copy, nontemporal (write-once output)
    float* outp = out + (size_t)((n * 3 + a) * HWQ + sp_base) * CH;
    for (int i = tid; i < CH * (TILE / 4); i += 256) {
        const f32x4 v4 = *reinterpret_cast<const f32x4*>(&lds[i * 4]);
        __builtin_nontemporal_store(v4, reinterpret_cast<f32x4*>(outp + (size_t)i * 4));
    }
}

extern "C" void kernel_launch(void* const* d_in, const int* in_sizes, int n_in,
                              void* d_out, int out_size, void* d_ws, size_t ws_size,
                              hipStream_t stream)
{
    const float* x = (const float*)d_in[0];
    float* out = (float*)d_out;
    dim3 grid(HWQ / TILE, 3, 32);   // (100, A, N)
    dim3 block(256);
    yolo_decode_kernel<<<grid, block, 0, stream>>>(x, out);
}

// Round 5
// 64.658 us; speedup vs baseline: 1.6611x; 1.0180x over previous
//
#include <hip/hip_runtime.h>
#include <cstddef>

// YOLO decode: x[N, A*(C+5), H, W] fp32 -> out[N, A*H*W, C+5] fp32
// N=32, A=3, C=80, H=W=80, IMG=640 (scale = IMG*IMG = 409600 on boxes)
// anchors: (10,13),(16,30),(33,23)
//
// Transform applied in the LOAD phase (channel uniform per 16-lane group).
// Store phase is a pure LDS->global copy issued as inline-asm
// global_store_dwordx4 sc0 sc1 nt: full write-around so the 209 MB output
// stream does not allocate in L2/L3 -> the 209 MB input (< 256 MB L3) can
// stay L3-resident across graph replays. A/B vs R4 (nt-only): if FETCH_SIZE
// and dur_us don't move, we are HBM-copy-bound at the 6.3 TB/s ceiling.

#define HWQ   6400   // H*W
#define WQ    80
#define CH    85     // C+5
#define TILE  64     // spatial positions per block
#define SCALE 409600.0f

typedef float f32x4 __attribute__((ext_vector_type(4)));

__global__ __launch_bounds__(256) void yolo_decode_kernel(
    const float* __restrict__ x, float* __restrict__ out)
{
    const int tile = blockIdx.x;   // 0..99   (HW/TILE)
    const int a    = blockIdx.y;   // 0..2
    const int n    = blockIdx.z;   // 0..31
    const int tid  = threadIdx.x;

    // spatial-major: element (s, c) at lds[s*85 + c].
    // Write phase: dword stride 340 -> bank stride 20 per s4-step, +1 per
    // channel group -> 2 lanes/bank = free. Read phase: contiguous b128.
    __shared__ __align__(16) float lds[TILE * CH];  // 21760 B

    const int sp_base = tile * TILE;
    const float* inp = x + ((size_t)(n * 3 + a) * CH) * HWQ + sp_base;

    const float awS = ((a == 0) ? 10.0f : ((a == 1) ? 16.0f : 33.0f)) * SCALE;
    const float ahS = ((a == 0) ? 13.0f : ((a == 1) ? 30.0f : 23.0f)) * SCALE;

    // ---- load + transform: coalesced float4 along spatial, channel uniform per quad
    for (int i = tid; i < CH * (TILE / 4); i += 256) {
        const int ch = i >> 4;        // channel 0..84 (constant for this quad)
        const int s4 = i & 15;        // spatial quad 0..15
        const f32x4 v = *reinterpret_cast<const f32x4*>(inp + (size_t)ch * HWQ + s4 * 4);

        const bool  iswh = (ch == 2) | (ch == 3);
        const float sgn  = iswh ? 1.0f : -1.0f;

        const int sp0 = sp_base + s4 * 4;
        const int gy0 = sp0 / WQ;
        const int gx0 = sp0 - gy0 * WQ;   // multiple of 4 -> gx0+3 <= 79, no wrap
        float addf = (ch == 0) ? (float)gx0 : ((ch == 1) ? (float)gy0 : 0.0f);
        const float step = (ch == 0) ? 1.0f : 0.0f;
        const float mulc = (ch < 2) ? SCALE
                         : ((ch == 2) ? awS : ((ch == 3) ? ahS : 1.0f));

        float r[4];
#pragma unroll
        for (int t = 0; t < 4; ++t) {
            const float e    = __expf(v[t] * sgn);
            const float sg   = __builtin_amdgcn_rcpf(1.0f + e);
            const float base = iswh ? e : sg;
            r[t] = (base + addf) * mulc;   // ch>=4: (sg+0)*1 = sigmoid exactly
            addf += step;
        }

        const int sb = s4 * 4;
        lds[(sb + 0) * CH + ch] = r[0];
        lds[(sb + 1) * CH + ch] = r[1];
        lds[(sb + 2) * CH + ch] = r[2];
        lds[(sb + 3) * CH + ch] = r[3];
    }
    __syncthreads();

    // ---- store: pure contiguous copy, full write-around (sc0 sc1 nt)
    float* outp = out + (size_t)((n * 3 + a) * HWQ + sp_base) * CH;
    for (int i = tid; i < CH * (TILE / 4); i += 256) {
        const f32x4 v4 = *reinterpret_cast<const f32x4*>(&lds[i * 4]);
        float* p = outp + (size_t)i * 4;
        asm volatile("global_store_dwordx4 %0, %1, off sc0 sc1 nt"
                     :
                     : "v"(p), "v"(v4)
                     : "memory");
    }
}

extern "C" void kernel_launch(void* const* d_in, const int* in_sizes, int n_in,
                              void* d_out, int out_size, void* d_ws, size_t ws_size,
                              hipStream_t stream)
{
    const float* x = (const float*)d_in[0];
    float* out = (float*)d_out;
    dim3 grid(HWQ / TILE, 3, 32);   // (100, A, N)
    dim3 block(256);
    yolo_decode_kernel<<<grid, block, 0, stream>>>(x, out);
}